// Round 5
// baseline (5199.371 us; speedup 1.0000x reference)
//
#include <hip/hip_runtime.h>
#include <hip/hip_bf16.h>
#include <math.h>

// ---------- constants (fixed problem shape) ----------
#define BATCH 8
#define CCH 192
#define LTOK 16384            // 128*128
#define BL 131072LL           // BATCH * LTOK
#define NWIN 2048             // BATCH * 16 * 16
#define NHEADS 6

typedef __hip_bfloat16 bf16;
typedef __bf16 bfr;  // raw bf16 for MFMA fragments
typedef bfr bf16x8 __attribute__((ext_vector_type(8)));
typedef float f32x4 __attribute__((ext_vector_type(4)));

// ---------- dtype flags (1 = f32, 0 = bf16), probed at runtime ----------
#define FX     0
#define FN1W   1
#define FN1B   2
#define FQKVW  3
#define FPROJW 4
#define FPROJB 5
#define FBIAS  6
#define FCONVW 7
#define FCG1   8
#define FCG2   9
#define FN2W   10
#define FN2B   11
#define FFC1   12
#define FSMIX  13
#define FFC2   14

struct InPtrs { const void* p[15]; int n[15]; };

__device__ __forceinline__ float ldin(const void* p, long long i, int f32) {
    return f32 ? ((const float*)p)[i]
               : __bfloat162float(((const bf16*)p)[i]);
}

__device__ __forceinline__ float gelu_f(float v) {
    return 0.5f * v * (1.0f + erff(v * 0.70710678118654752f));
}

// ---------- dtype probe: one block per tensor ----------
// Read as bf16. f32 signature: any NaN/|v|>1e9 sample (random f32 low-halves
// hit this w.p. ~0.38/sample -> certain detection), OR even-all-zero &&
// odd-nonzero (f32 "ones"-like tensors). All-zero tensors: dtype-agnostic.
__global__ void probe_k(InPtrs in, int* flags) {
    __shared__ int s_insane, s_evennz, s_oddnz;
    if (threadIdx.x == 0) { s_insane = 0; s_evennz = 0; s_oddnz = 0; }
    __syncthreads();
    int t = blockIdx.x;
    const bf16* p = (const bf16*)in.p[t];
    int n = in.n[t];
    int m = n < 2048 ? n : 2048;
    bool insane = false, evennz = false, oddnz = false;
    for (int i = threadIdx.x; i < m; i += 256) {
        float v = __bfloat162float(p[i]);
        if (!(fabsf(v) <= 1e9f)) insane = true;   // NaN/inf/huge
        if (v != 0.0f) { if (i & 1) oddnz = true; else evennz = true; }
    }
    if (insane) s_insane = 1;
    if (evennz) s_evennz = 1;
    if (oddnz)  s_oddnz = 1;
    __syncthreads();
    if (threadIdx.x == 0)
        flags[t] = (s_insane || (!s_evennz && s_oddnz)) ? 1 : 0;
}

// ---------- weight transpose + downcast: W[K,N] -> WT[N,K] bf16 ----------
__global__ void transpose_k(const void* __restrict__ W, bf16* __restrict__ WT,
                            int K, int N, const int* flag) {
    int f = *flag;
    int idx = blockIdx.x * 256 + threadIdx.x;
    if (idx >= K * N) return;
    int k = idx / N, n = idx % N;
    WT[(long long)n * K + k] = __float2bfloat16(ldin(W, idx, f));
}

// ---------- LayerNorm (one wave per token, C=192) -> bf16 ----------
__global__ __launch_bounds__(256)
void ln_kernel(const void* __restrict__ x, const void* __restrict__ w,
               const void* __restrict__ b, bf16* __restrict__ out,
               const int* flags) {
    int fx = flags[FX], fw = flags[FN1W], fb = flags[FN1B];
    int wv = threadIdx.x >> 6, lane = threadIdx.x & 63;
    long long t = (long long)blockIdx.x * 4 + wv;
    long long base = t * CCH;
    float v0 = ldin(x, base + lane, fx);
    float v1 = ldin(x, base + lane + 64, fx);
    float v2 = ldin(x, base + lane + 128, fx);
    float s = v0 + v1 + v2;
    for (int o = 32; o; o >>= 1) s += __shfl_xor(s, o);
    float mean = s * (1.0f / 192.0f);
    float d0 = v0 - mean, d1 = v1 - mean, d2 = v2 - mean;
    float vs = d0 * d0 + d1 * d1 + d2 * d2;
    for (int o = 32; o; o >>= 1) vs += __shfl_xor(vs, o);
    float rstd = rsqrtf(vs * (1.0f / 192.0f) + 1e-5f);
    bf16* op = out + base;
    op[lane]       = __float2bfloat16(d0 * rstd * ldin(w, lane, fw)       + ldin(b, lane, fb));
    op[lane + 64]  = __float2bfloat16(d1 * rstd * ldin(w, lane + 64, fw)  + ldin(b, lane + 64, fb));
    op[lane + 128] = __float2bfloat16(d2 * rstd * ldin(w, lane + 128, fw) + ldin(b, lane + 128, fb));
}

// ---------- MFMA GEMM: C[M,N] = A[M,K] @ BT[N,K]^T, bf16 A/B, f32 acc ----------
// CT = output element type (bf16 intermediates, float for final into d_out).
// EPI: 0 none, 1 +bias[col], 2 gelu, 3 +res[f32] (res may alias Cmat: same-thread RMW)
template<int EPI, int KK, typename CT>
__global__ __launch_bounds__(256)
void gemm_bt(const bf16* __restrict__ A_, const bf16* __restrict__ BT_,
             CT* Cmat, int N,
             const void* __restrict__ bias, const float* res, const int* flags) {
    const bfr* A = reinterpret_cast<const bfr*>(A_);
    const bfr* BT = reinterpret_cast<const bfr*>(BT_);
    int fb = (EPI == 1) ? flags[FPROJB] : 0;
    int lane = threadIdx.x & 63;
    int wv = threadIdx.x >> 6;
    long long m0 = (long long)blockIdx.x * 64 + wv * 16;
    int n0 = blockIdx.y * 64;
    int r16 = lane & 15, q = lane >> 4;

    const bfr* ap = A + (m0 + r16) * KK + q * 8;
    const bfr* bp = BT + (long long)(n0 + r16) * KK + q * 8;

    f32x4 acc0 = {0.f, 0.f, 0.f, 0.f};
    f32x4 acc1 = {0.f, 0.f, 0.f, 0.f};
    f32x4 acc2 = {0.f, 0.f, 0.f, 0.f};
    f32x4 acc3 = {0.f, 0.f, 0.f, 0.f};

#pragma unroll
    for (int k0 = 0; k0 < KK; k0 += 32) {
        bf16x8 a  = *reinterpret_cast<const bf16x8*>(ap + k0);
        bf16x8 b0 = *reinterpret_cast<const bf16x8*>(bp + k0);
        bf16x8 b1 = *reinterpret_cast<const bf16x8*>(bp + 16 * KK + k0);
        bf16x8 b2 = *reinterpret_cast<const bf16x8*>(bp + 32 * KK + k0);
        bf16x8 b3 = *reinterpret_cast<const bf16x8*>(bp + 48 * KK + k0);
        acc0 = __builtin_amdgcn_mfma_f32_16x16x32_bf16(a, b0, acc0, 0, 0, 0);
        acc1 = __builtin_amdgcn_mfma_f32_16x16x32_bf16(a, b1, acc1, 0, 0, 0);
        acc2 = __builtin_amdgcn_mfma_f32_16x16x32_bf16(a, b2, acc2, 0, 0, 0);
        acc3 = __builtin_amdgcn_mfma_f32_16x16x32_bf16(a, b3, acc3, 0, 0, 0);
    }

    f32x4 accs[4] = {acc0, acc1, acc2, acc3};
#pragma unroll
    for (int j = 0; j < 4; ++j) {
        int col = n0 + j * 16 + r16;
#pragma unroll
        for (int r = 0; r < 4; ++r) {
            long long row = m0 + q * 4 + r;
            float v = accs[j][r];
            if (EPI == 1) v += ldin(bias, col, fb);
            if (EPI == 2) v = gelu_f(v);
            if (EPI == 3) v += res[row * N + col];
            Cmat[row * N + col] = (CT)v;
        }
    }
}

// ---------- window attention (one block per (window, head)) ----------
__global__ __launch_bounds__(256)
void attn_kernel(const bf16* __restrict__ qkv, const void* __restrict__ bias,
                 bf16* __restrict__ attn_cat, const int* flags) {
    __shared__ float qs[64][33], ks[64][33], vs[64][33];
    __shared__ float Ps[64][65];
    __shared__ float redmax[64][4], redsum[64][4];

    int fbias = flags[FBIAS];
    int w = blockIdx.x, h = blockIdx.y;
    int b = w >> 8, rem = w & 255, wy = rem >> 4, wx = rem & 15;
    int tid = threadIdx.x;
    int i = tid >> 2, part = tid & 3;

    {
        int py = i >> 3, px = i & 7;
        long long t = (long long)b * LTOK + (long long)((wy * 8 + py) * 128 + wx * 8 + px);
        const bf16* base = qkv + t * 576 + h * 32 + part * 8;
#pragma unroll
        for (int j = 0; j < 8; ++j) {
            qs[i][part * 8 + j] = __bfloat162float(base[j]) * 0.17677669529663689f; // 1/sqrt(32)
            ks[i][part * 8 + j] = __bfloat162float(base[192 + j]);
            vs[i][part * 8 + j] = __bfloat162float(base[384 + j]);
        }
    }
    __syncthreads();

    long long bb = (long long)h * 4096 + i * 64;
    float lg[16];
    float mloc = -1e30f;
#pragma unroll
    for (int jj = 0; jj < 16; ++jj) {
        int j = part * 16 + jj;
        float d = 0.f;
#pragma unroll
        for (int c = 0; c < 32; ++c) d += qs[i][c] * ks[j][c];
        d += ldin(bias, bb + j, fbias);
        lg[jj] = d;
        mloc = fmaxf(mloc, d);
    }
    redmax[i][part] = mloc;
    __syncthreads();
    float m = fmaxf(fmaxf(redmax[i][0], redmax[i][1]), fmaxf(redmax[i][2], redmax[i][3]));
    float sloc = 0.f;
#pragma unroll
    for (int jj = 0; jj < 16; ++jj) {
        float e = __expf(lg[jj] - m);
        Ps[i][part * 16 + jj] = e;
        sloc += e;
    }
    redsum[i][part] = sloc;
    __syncthreads();
    float inv = 1.0f / (redsum[i][0] + redsum[i][1] + redsum[i][2] + redsum[i][3]);

    float o[8] = {0.f, 0.f, 0.f, 0.f, 0.f, 0.f, 0.f, 0.f};
    for (int j = 0; j < 64; ++j) {
        float p = Ps[i][j];
#pragma unroll
        for (int dd = 0; dd < 8; ++dd) o[dd] += p * vs[j][part * 8 + dd];
    }
    long long orow = (long long)w * 64 + i;
    bf16* op = attn_cat + orow * CCH + h * 32 + part * 8;
#pragma unroll
    for (int dd = 0; dd < 8; ++dd) op[dd] = __float2bfloat16(o[dd] * inv);
}

// ---------- depthwise 3x3 conv (channels-last), optional exact gelu ----------
template<bool GELU, int CX>
__global__ void dwconv_k(const bf16* __restrict__ in, const void* __restrict__ wgt,
                         bf16* __restrict__ out, const int* wflag) {
    int f = *wflag;
    long long idx = (long long)blockIdx.x * 256 + threadIdx.x;
    if (idx >= BL * CX) return;
    int c = (int)(idx % CX);
    long long bl = idx / CX;
    int l = (int)(bl % LTOK);
    int b = (int)(bl / LTOK);
    int y = l >> 7, x = l & 127;
    float acc = 0.f;
#pragma unroll
    for (int dy = -1; dy <= 1; ++dy) {
        int yy = y + dy;
        if (yy < 0 || yy > 127) continue;
#pragma unroll
        for (int dx = -1; dx <= 1; ++dx) {
            int xx = x + dx;
            if (xx < 0 || xx > 127) continue;
            float wv = ldin(wgt, c * 9 + (dy + 1) * 3 + (dx + 1), f);
            acc += __bfloat162float(in[((long long)b * LTOK + yy * 128 + xx) * CX + c]) * wv;
        }
    }
    if (GELU) acc = gelu_f(acc);
    out[idx] = __float2bfloat16(acc);
}

// ---------- pooled partial sums (conv_feat mean over L) ----------
__global__ void pool_k(const bf16* __restrict__ conv, float* __restrict__ pooled) {
    int b = blockIdx.x, chunk = blockIdx.y, c = threadIdx.x; // blockDim 192
    float s = 0.f;
    long long base = ((long long)b * LTOK + chunk * 256) * CCH + c;
    for (int l = 0; l < 256; ++l) s += __bfloat162float(conv[base + (long long)l * CCH]);
    atomicAdd(&pooled[b * CCH + c], s);
}

// ---------- channel gate: cm = sigmoid(gelu(pooled@cg1^T)@cg2^T) ----------
__global__ void cm_k(const float* __restrict__ pooled, const void* __restrict__ w1,
                     const void* __restrict__ w2, float* __restrict__ cm,
                     const int* flags) {
    __shared__ float ps[192], g[24];
    int f1 = flags[FCG1], f2 = flags[FCG2];
    int b = blockIdx.x, c = threadIdx.x; // blockDim 192
    ps[c] = pooled[b * CCH + c] * (1.0f / 16384.0f);
    __syncthreads();
    if (c < 24) {
        float t = 0.f;
        for (int k = 0; k < 192; ++k) t += ps[k] * ldin(w1, c * 192 + k, f1);
        g[c] = gelu_f(t);
    }
    __syncthreads();
    float s = 0.f;
#pragma unroll
    for (int r = 0; r < 24; ++r) s += g[r] * ldin(w2, c * 24 + r, f2);
    cm[b * CCH + c] = 1.0f / (1.0f + expf(-s));
}

// ---------- x2 = x + attn*cm + conv; write x2 (f32, into d_out) and n2 = LN(x2) ----------
__global__ __launch_bounds__(256)
void x2ln2_k(const void* __restrict__ x, const bf16* __restrict__ attnf,
             const bf16* __restrict__ conv, const float* __restrict__ cm,
             const void* __restrict__ w, const void* __restrict__ bb,
             float* __restrict__ x2, bf16* __restrict__ n2, const int* flags) {
    int fx = flags[FX], fw = flags[FN2W], fb = flags[FN2B];
    int wv = threadIdx.x >> 6, lane = threadIdx.x & 63;
    long long t = (long long)blockIdx.x * 4 + wv;
    int b = (int)(t >> 14);
    int l = (int)(t & 16383);
    int y = l >> 7, xx = l & 127;
    long long wrow = ((long long)b * 256 + (y >> 3) * 16 + (xx >> 3)) * 64 + (y & 7) * 8 + (xx & 7);

    float v[3];
#pragma unroll
    for (int k = 0; k < 3; ++k) {
        int c = lane + 64 * k;
        float val = ldin(x, t * CCH + c, fx)
                  + __bfloat162float(attnf[wrow * CCH + c]) * cm[b * CCH + c]
                  + __bfloat162float(conv[t * CCH + c]);
        v[k] = val;
        x2[t * CCH + c] = val;
    }
    float s = v[0] + v[1] + v[2];
    for (int o = 32; o; o >>= 1) s += __shfl_xor(s, o);
    float mean = s * (1.0f / 192.0f);
    float d[3] = {v[0] - mean, v[1] - mean, v[2] - mean};
    float vs = d[0] * d[0] + d[1] * d[1] + d[2] * d[2];
    for (int o = 32; o; o >>= 1) vs += __shfl_xor(vs, o);
    float rstd = rsqrtf(vs * (1.0f / 192.0f) + 1e-5f);
#pragma unroll
    for (int k = 0; k < 3; ++k) {
        int c = lane + 64 * k;
        n2[t * CCH + c] = __float2bfloat16(d[k] * rstd * ldin(w, c, fw) + ldin(bb, c, fb));
    }
}

// ---------- launch ----------
// Inputs: dtype probed per tensor (expected all f32). OUTPUT: float32 in d_out
// (R3/R4's exact sqrt(2)*maxref error signature = bf16 written into f32 buffer).
// Intermediates bf16. Workspace (peak ~252.3 MB, lifetime-overlaid):
//   Rbig [151 MB]: qkv (qkv-gemm -> attn); then h=fc1-out [0,100.7MB) (fc1 -> smix),
//                  attnf [100.7,151) (proj -> x2ln2). Lifetimes disjoint.
//   Rpair[100.7MB]: front = n1 (ln1 -> dwconv) then n2 (x2ln2 -> fc1);
//                   back = cat (attn -> proj) then convf (dwconv -> x2ln2);
//                   whole region = h2 (smix -> final gemm).
//   x2 lives in d_out (f32); final gemm does same-thread in-place RMW on d_out.
extern "C" void kernel_launch(void* const* d_in, const int* in_sizes, int n_in,
                              void* d_out, int out_size, void* d_ws, size_t ws_size,
                              hipStream_t stream) {
    (void)n_in; (void)out_size; (void)ws_size;
    float* out = (float*)d_out;

    char* wsp = (char*)d_ws;
    size_t off = 0;
    auto alloc = [&](size_t bytes) -> char* {
        char* p = wsp + off;
        off += (bytes + 255) & ~(size_t)255;
        return p;
    };
    int*  flags   = (int*)alloc(15 * 4);
    bf16* qkv_wT  = (bf16*)alloc(576 * 192 * 2);
    bf16* proj_wT = (bf16*)alloc(192 * 192 * 2);
    bf16* fc1_wT  = (bf16*)alloc(384 * 192 * 2);
    bf16* fc2_wT  = (bf16*)alloc(192 * 384 * 2);
    float* pooled = (float*)alloc(BATCH * CCH * 4);
    float* cm     = (float*)alloc(BATCH * CCH * 4);
    char* Rbig    = alloc(BL * 576 * 2);          // 150,994,944 B
    char* Rpair   = alloc(BL * 384 * 2);          // 100,663,296 B

    bf16* qkvb  = (bf16*)Rbig;                               // [BL,576]
    bf16* hbuf  = (bf16*)Rbig;                               // [BL,384] (after attn)
    bf16* attnf = (bf16*)(Rbig + (size_t)BL * 384 * 2);      // [BL,192] (tail of Rbig)
    bf16* n1    = (bf16*)Rpair;                              // [BL,192] -> n2
    bf16* cat   = (bf16*)(Rpair + (size_t)BL * 192 * 2);     // [BL,192] -> convf
    bf16* n2    = n1;
    bf16* convf = cat;
    bf16* h2    = (bf16*)Rpair;                              // [BL,384] (after fc1)
    float* x2   = out;                                       // x2 lives in d_out (f32)

    // input tensor table (skipping H=d_in[1], W=d_in[2])
    const int imap[15] = {0, 3, 4, 5, 6, 7, 8, 9, 10, 11, 12, 13, 14, 15, 16};
    InPtrs ip;
    for (int i = 0; i < 15; ++i) { ip.p[i] = d_in[imap[i]]; ip.n[i] = in_sizes[imap[i]]; }
    const void* x        = d_in[0];
    const void* qkv_w    = d_in[5];
    const void* proj_w   = d_in[6];
    const void* proj_b   = d_in[7];
    const void* attnbias = d_in[8];
    const void* conv_w   = d_in[9];
    const void* cg_w1    = d_in[10];
    const void* cg_w2    = d_in[11];
    const void* fc1_w    = d_in[14];
    const void* smix_w   = d_in[15];
    const void* fc2_w    = d_in[16];

    // dtype probe first
    probe_k<<<15, 256, 0, stream>>>(ip, flags);

    // weight transposes + downcast (tiny)
    transpose_k<<<(192 * 576 + 255) / 256, 256, 0, stream>>>(qkv_w, qkv_wT, 192, 576, flags + FQKVW);
    transpose_k<<<(192 * 192 + 255) / 256, 256, 0, stream>>>(proj_w, proj_wT, 192, 192, flags + FPROJW);
    transpose_k<<<(192 * 384 + 255) / 256, 256, 0, stream>>>(fc1_w, fc1_wT, 192, 384, flags + FFC1);
    transpose_k<<<(384 * 192 + 255) / 256, 256, 0, stream>>>(fc2_w, fc2_wT, 384, 192, flags + FFC2);
    hipMemsetAsync(pooled, 0, BATCH * CCH * 4, stream);

    // LN1
    ln_kernel<<<BL / 4, 256, 0, stream>>>(x, d_in[3], d_in[4], n1, flags);
    // qkv = n1 @ qkv_w  [BL,576]
    gemm_bt<0, 192, bf16><<<dim3(BL / 64, 576 / 64), 256, 0, stream>>>(n1, qkv_wT, qkvb, 576, nullptr, nullptr, flags);
    // window attention -> cat (window-ordered)
    attn_kernel<<<dim3(NWIN, NHEADS), 256, 0, stream>>>(qkvb, attnbias, cat, flags);
    // proj: attnf = cat @ proj_w + proj_b (window-ordered); qkv region now dead
    gemm_bt<1, 192, bf16><<<dim3(BL / 64, 192 / 64), 256, 0, stream>>>(cat, proj_wT, attnf, 192, proj_b, nullptr, flags);
    // conv branch: conv_feat = gelu(dwconv(n1)); overwrites cat (dead after proj)
    dwconv_k<true, 192><<<(BL * 192 + 255) / 256, 256, 0, stream>>>(n1, conv_w, convf, flags + FCONVW);
    // AIM gate
    pool_k<<<dim3(BATCH, 64), 192, 0, stream>>>(convf, pooled);
    cm_k<<<BATCH, 192, 0, stream>>>(pooled, cg_w1, cg_w2, cm, flags);
    // x2 (f32 -> d_out) + LN2 (n2 overwrites n1)
    x2ln2_k<<<BL / 4, 256, 0, stream>>>(x, attnf, convf, cm, d_in[12], d_in[13], x2, n2, flags);
    // FFN: h = gelu(n2 @ fc1_w) into front of Rbig (qkv+attnf dead)
    gemm_bt<2, 192, bf16><<<dim3(BL / 64, 384 / 64), 256, 0, stream>>>(n2, fc1_wT, hbuf, 384, nullptr, nullptr, flags);
    // spatial mix dwconv -> h2 (overwrites n2+convf, both dead)
    dwconv_k<false, 384><<<(BL * 384 + 255) / 256, 256, 0, stream>>>(hbuf, smix_w, h2, flags + FSMIX);
    // out = x2 + h2 @ fc2_w   (in-place f32 RMW on d_out)
    gemm_bt<3, 384, float><<<dim3(BL / 64, 192 / 64), 256, 0, stream>>>(h2, fc2_wT, out, 192, nullptr, x2, flags);
}

// Round 6
// 1670.302 us; speedup vs baseline: 3.1128x; 3.1128x over previous
//
#include <hip/hip_runtime.h>
#include <hip/hip_bf16.h>
#include <math.h>

// ---------- constants (fixed problem shape) ----------
#define BATCH 8
#define CCH 192
#define LTOK 16384            // 128*128
#define BL 131072LL           // BATCH * LTOK
#define NWIN 2048             // BATCH * 16 * 16
#define NHEADS 6

typedef __hip_bfloat16 bf16;
typedef __bf16 bfr;  // raw bf16 for MFMA fragments
typedef bfr bf16x8 __attribute__((ext_vector_type(8)));
typedef float f32x4 __attribute__((ext_vector_type(4)));

// ---------- dtype flags (1 = f32, 0 = bf16), probed at runtime ----------
#define FX     0
#define FN1W   1
#define FN1B   2
#define FQKVW  3
#define FPROJW 4
#define FPROJB 5
#define FBIAS  6
#define FCONVW 7
#define FCG1   8
#define FCG2   9
#define FN2W   10
#define FN2B   11
#define FFC1   12
#define FSMIX  13
#define FFC2   14

struct InPtrs { const void* p[15]; int n[15]; };

__device__ __forceinline__ float ldin(const void* p, long long i, int f32) {
    return f32 ? ((const float*)p)[i]
               : __bfloat162float(((const bf16*)p)[i]);
}

__device__ __forceinline__ float gelu_f(float v) {
    return 0.5f * v * (1.0f + erff(v * 0.70710678118654752f));
}

// ---------- dtype probe: one block per tensor ----------
__global__ void probe_k(InPtrs in, int* flags) {
    __shared__ int s_insane, s_evennz, s_oddnz;
    if (threadIdx.x == 0) { s_insane = 0; s_evennz = 0; s_oddnz = 0; }
    __syncthreads();
    int t = blockIdx.x;
    const bf16* p = (const bf16*)in.p[t];
    int n = in.n[t];
    int m = n < 2048 ? n : 2048;
    bool insane = false, evennz = false, oddnz = false;
    for (int i = threadIdx.x; i < m; i += 256) {
        float v = __bfloat162float(p[i]);
        if (!(fabsf(v) <= 1e9f)) insane = true;   // NaN/inf/huge
        if (v != 0.0f) { if (i & 1) oddnz = true; else evennz = true; }
    }
    if (insane) s_insane = 1;
    if (evennz) s_evennz = 1;
    if (oddnz)  s_oddnz = 1;
    __syncthreads();
    if (threadIdx.x == 0)
        flags[t] = (s_insane || (!s_evennz && s_oddnz)) ? 1 : 0;
}

// ---------- weight transpose + downcast: W[K,N] -> WT[N,K] bf16 ----------
__global__ void transpose_k(const void* __restrict__ W, bf16* __restrict__ WT,
                            int K, int N, const int* flag) {
    int f = *flag;
    int idx = blockIdx.x * 256 + threadIdx.x;
    if (idx >= K * N) return;
    int k = idx / N, n = idx % N;
    WT[(long long)n * K + k] = __float2bfloat16(ldin(W, idx, f));
}

// ---------- LayerNorm (one wave per token, C=192) -> bf16 ----------
__global__ __launch_bounds__(256)
void ln_kernel(const void* __restrict__ x, const void* __restrict__ w,
               const void* __restrict__ b, bf16* __restrict__ out,
               const int* flags) {
    int fx = flags[FX], fw = flags[FN1W], fb = flags[FN1B];
    int wv = threadIdx.x >> 6, lane = threadIdx.x & 63;
    long long t = (long long)blockIdx.x * 4 + wv;
    long long base = t * CCH;
    float v0 = ldin(x, base + lane, fx);
    float v1 = ldin(x, base + lane + 64, fx);
    float v2 = ldin(x, base + lane + 128, fx);
    float s = v0 + v1 + v2;
    for (int o = 32; o; o >>= 1) s += __shfl_xor(s, o);
    float mean = s * (1.0f / 192.0f);
    float d0 = v0 - mean, d1 = v1 - mean, d2 = v2 - mean;
    float vs = d0 * d0 + d1 * d1 + d2 * d2;
    for (int o = 32; o; o >>= 1) vs += __shfl_xor(vs, o);
    float rstd = rsqrtf(vs * (1.0f / 192.0f) + 1e-5f);
    bf16* op = out + base;
    op[lane]       = __float2bfloat16(d0 * rstd * ldin(w, lane, fw)       + ldin(b, lane, fb));
    op[lane + 64]  = __float2bfloat16(d1 * rstd * ldin(w, lane + 64, fw)  + ldin(b, lane + 64, fb));
    op[lane + 128] = __float2bfloat16(d2 * rstd * ldin(w, lane + 128, fw) + ldin(b, lane + 128, fb));
}

// ---------- MFMA GEMM: C[M,N] = A[M,K] @ BT[N,K]^T, bf16 A/B, f32 acc ----------
template<int EPI, int KK, typename CT>
__global__ __launch_bounds__(256)
void gemm_bt(const bf16* __restrict__ A_, const bf16* __restrict__ BT_,
             CT* Cmat, int N,
             const void* __restrict__ bias, const float* res, const int* flags) {
    const bfr* A = reinterpret_cast<const bfr*>(A_);
    const bfr* BT = reinterpret_cast<const bfr*>(BT_);
    int fb = (EPI == 1) ? flags[FPROJB] : 0;
    int lane = threadIdx.x & 63;
    int wv = threadIdx.x >> 6;
    long long m0 = (long long)blockIdx.x * 64 + wv * 16;
    int n0 = blockIdx.y * 64;
    int r16 = lane & 15, q = lane >> 4;

    const bfr* ap = A + (m0 + r16) * KK + q * 8;
    const bfr* bp = BT + (long long)(n0 + r16) * KK + q * 8;

    f32x4 acc0 = {0.f, 0.f, 0.f, 0.f};
    f32x4 acc1 = {0.f, 0.f, 0.f, 0.f};
    f32x4 acc2 = {0.f, 0.f, 0.f, 0.f};
    f32x4 acc3 = {0.f, 0.f, 0.f, 0.f};

#pragma unroll
    for (int k0 = 0; k0 < KK; k0 += 32) {
        bf16x8 a  = *reinterpret_cast<const bf16x8*>(ap + k0);
        bf16x8 b0 = *reinterpret_cast<const bf16x8*>(bp + k0);
        bf16x8 b1 = *reinterpret_cast<const bf16x8*>(bp + 16 * KK + k0);
        bf16x8 b2 = *reinterpret_cast<const bf16x8*>(bp + 32 * KK + k0);
        bf16x8 b3 = *reinterpret_cast<const bf16x8*>(bp + 48 * KK + k0);
        acc0 = __builtin_amdgcn_mfma_f32_16x16x32_bf16(a, b0, acc0, 0, 0, 0);
        acc1 = __builtin_amdgcn_mfma_f32_16x16x32_bf16(a, b1, acc1, 0, 0, 0);
        acc2 = __builtin_amdgcn_mfma_f32_16x16x32_bf16(a, b2, acc2, 0, 0, 0);
        acc3 = __builtin_amdgcn_mfma_f32_16x16x32_bf16(a, b3, acc3, 0, 0, 0);
    }

    f32x4 accs[4] = {acc0, acc1, acc2, acc3};
#pragma unroll
    for (int j = 0; j < 4; ++j) {
        int col = n0 + j * 16 + r16;
#pragma unroll
        for (int r = 0; r < 4; ++r) {
            long long row = m0 + q * 4 + r;
            float v = accs[j][r];
            if (EPI == 1) v += ldin(bias, col, fb);
            if (EPI == 2) v = gelu_f(v);
            if (EPI == 3) v += res[row * N + col];
            Cmat[row * N + col] = (CT)v;
        }
    }
}

// ---------- MFMA window attention: one wave per (window, head) ----------
// S = (Q*scale)K^T + bias via 16 mfma_16x16x32; softmax in C-layout regs
// (row = quad*4+reg lives in one 16-lane quad -> shfl_xor 1/2/4/8 row-reduce);
// P -> LDS (bf16, A-layout reads); V -> LDS transposed; PV via 16 mfma.
__global__ __launch_bounds__(256)
void attn_mfma_k(const bf16* __restrict__ qkv, const void* __restrict__ bias,
                 bf16* __restrict__ attn_cat, const int* flags) {
    __shared__ __align__(16) bfr Vt[4][32][72];   // [wave][n][token(k)]  pad 8
    __shared__ __align__(16) bfr Pb[4][64][72];   // [wave][row][col]     pad 8

    const int fbias = flags[FBIAS];
    const int wv = threadIdx.x >> 6, lane = threadIdx.x & 63;
    const int pair = blockIdx.x * 4 + wv;          // 12288 pairs
    const int w = pair / 6, h = pair - w * 6;
    const int b = w >> 8, rem = w & 255, wy = rem >> 4, wx = rem & 15;
    const int l15 = lane & 15, quad = lane >> 4;
    const long long tokbase = (long long)b * LTOK + (wy * 8) * 128 + wx * 8;

    // ---- phase 1: V -> Vt transposed (lane = token) ----
    {
        long long t = tokbase + (lane >> 3) * 128 + (lane & 7);
        const bfr* vp = (const bfr*)(qkv + t * 576 + 384 + h * 32);
        bf16x8 v0 = *(const bf16x8*)(vp);
        bf16x8 v1 = *(const bf16x8*)(vp + 8);
        bf16x8 v2 = *(const bf16x8*)(vp + 16);
        bf16x8 v3 = *(const bf16x8*)(vp + 24);
#pragma unroll
        for (int j = 0; j < 8; ++j) {
            Vt[wv][j][lane]      = v0[j];
            Vt[wv][j + 8][lane]  = v1[j];
            Vt[wv][j + 16][lane] = v2[j];
            Vt[wv][j + 24][lane] = v3[j];
        }
    }

    // ---- phase 2: Q/K fragments direct from global ----
    bf16x8 aq[4], bk[4];
#pragma unroll
    for (int mt = 0; mt < 4; ++mt) {
        int i0 = mt * 16 + l15;
        long long t = tokbase + (i0 >> 3) * 128 + (i0 & 7);
        const bfr* qp = (const bfr*)(qkv + t * 576 + h * 32 + quad * 8);
        aq[mt] = *(const bf16x8*)qp;
        bk[mt] = *(const bf16x8*)(qp + 192);
    }

    // ---- phase 3: S = Q K^T ----
    f32x4 S[4][4];
#pragma unroll
    for (int mt = 0; mt < 4; ++mt)
#pragma unroll
        for (int nt = 0; nt < 4; ++nt) {
            f32x4 z = {0.f, 0.f, 0.f, 0.f};
            S[mt][nt] = __builtin_amdgcn_mfma_f32_16x16x32_bf16(aq[mt], bk[nt], z, 0, 0, 0);
        }

    // ---- phase 4: scale + bias + online-free softmax (full rows available) ----
    const float scale = 0.17677669529663689f;   // 1/sqrt(32)
    float linv[4][4];
    const long long bias0 = (long long)h * 4096;
#pragma unroll
    for (int mt = 0; mt < 4; ++mt) {
#pragma unroll
        for (int nt = 0; nt < 4; ++nt)
#pragma unroll
            for (int r = 0; r < 4; ++r) {
                long long bi = bias0 + (mt * 16 + quad * 4 + r) * 64 + nt * 16 + l15;
                S[mt][nt][r] = S[mt][nt][r] * scale + ldin(bias, bi, fbias);
            }
#pragma unroll
        for (int r = 0; r < 4; ++r) {
            float m = fmaxf(fmaxf(S[mt][0][r], S[mt][1][r]), fmaxf(S[mt][2][r], S[mt][3][r]));
            m = fmaxf(m, __shfl_xor(m, 1));
            m = fmaxf(m, __shfl_xor(m, 2));
            m = fmaxf(m, __shfl_xor(m, 4));
            m = fmaxf(m, __shfl_xor(m, 8));
            float l = 0.f;
#pragma unroll
            for (int nt = 0; nt < 4; ++nt) {
                float e = __expf(S[mt][nt][r] - m);
                S[mt][nt][r] = e;
                l += e;
            }
            l += __shfl_xor(l, 1);
            l += __shfl_xor(l, 2);
            l += __shfl_xor(l, 4);
            l += __shfl_xor(l, 8);
            linv[mt][r] = 1.0f / l;
        }
        // write P tile rows to LDS (bf16)
#pragma unroll
        for (int nt = 0; nt < 4; ++nt)
#pragma unroll
            for (int r = 0; r < 4; ++r) {
                bf16 pv = __float2bfloat16(S[mt][nt][r]);
                Pb[wv][mt * 16 + quad * 4 + r][nt * 16 + l15] = *(bfr*)&pv;
            }
    }

    __syncthreads();   // Vt + Pb visible (also intra-wave lgkm drain)

    // ---- phase 5: O = P @ V ----
    f32x4 O[4][2];
#pragma unroll
    for (int mt = 0; mt < 4; ++mt)
#pragma unroll
        for (int n2 = 0; n2 < 2; ++n2)
            O[mt][n2] = f32x4{0.f, 0.f, 0.f, 0.f};
#pragma unroll
    for (int kc = 0; kc < 2; ++kc) {
        bf16x8 bv0 = *(const bf16x8*)&Vt[wv][l15][kc * 32 + quad * 8];
        bf16x8 bv1 = *(const bf16x8*)&Vt[wv][16 + l15][kc * 32 + quad * 8];
#pragma unroll
        for (int mt = 0; mt < 4; ++mt) {
            bf16x8 ap = *(const bf16x8*)&Pb[wv][mt * 16 + l15][kc * 32 + quad * 8];
            O[mt][0] = __builtin_amdgcn_mfma_f32_16x16x32_bf16(ap, bv0, O[mt][0], 0, 0, 0);
            O[mt][1] = __builtin_amdgcn_mfma_f32_16x16x32_bf16(ap, bv1, O[mt][1], 0, 0, 0);
        }
    }

    // ---- phase 6: normalize + store (window-ordered rows) ----
#pragma unroll
    for (int mt = 0; mt < 4; ++mt)
#pragma unroll
        for (int n2 = 0; n2 < 2; ++n2)
#pragma unroll
            for (int r = 0; r < 4; ++r) {
                long long row = (long long)w * 64 + mt * 16 + quad * 4 + r;
                attn_cat[row * CCH + h * 32 + n2 * 16 + l15] =
                    __float2bfloat16(O[mt][n2][r] * linv[mt][r]);
            }
}

// ---------- depthwise 3x3 conv (channels-last), optional exact gelu ----------
template<bool GELU, int CX>
__global__ void dwconv_k(const bf16* __restrict__ in, const void* __restrict__ wgt,
                         bf16* __restrict__ out, const int* wflag) {
    int f = *wflag;
    long long idx = (long long)blockIdx.x * 256 + threadIdx.x;
    if (idx >= BL * CX) return;
    int c = (int)(idx % CX);
    long long bl = idx / CX;
    int l = (int)(bl % LTOK);
    int b = (int)(bl / LTOK);
    int y = l >> 7, x = l & 127;
    float acc = 0.f;
#pragma unroll
    for (int dy = -1; dy <= 1; ++dy) {
        int yy = y + dy;
        if (yy < 0 || yy > 127) continue;
#pragma unroll
        for (int dx = -1; dx <= 1; ++dx) {
            int xx = x + dx;
            if (xx < 0 || xx > 127) continue;
            float wv = ldin(wgt, c * 9 + (dy + 1) * 3 + (dx + 1), f);
            acc += __bfloat162float(in[((long long)b * LTOK + yy * 128 + xx) * CX + c]) * wv;
        }
    }
    if (GELU) acc = gelu_f(acc);
    out[idx] = __float2bfloat16(acc);
}

// ---------- pooled partial sums (conv_feat mean over L) ----------
__global__ void pool_k(const bf16* __restrict__ conv, float* __restrict__ pooled) {
    int b = blockIdx.x, chunk = blockIdx.y, c = threadIdx.x; // blockDim 192
    float s = 0.f;
    long long base = ((long long)b * LTOK + chunk * 256) * CCH + c;
    for (int l = 0; l < 256; ++l) s += __bfloat162float(conv[base + (long long)l * CCH]);
    atomicAdd(&pooled[b * CCH + c], s);
}

// ---------- channel gate: cm = sigmoid(gelu(pooled@cg1^T)@cg2^T) ----------
__global__ void cm_k(const float* __restrict__ pooled, const void* __restrict__ w1,
                     const void* __restrict__ w2, float* __restrict__ cm,
                     const int* flags) {
    __shared__ float ps[192], g[24];
    int f1 = flags[FCG1], f2 = flags[FCG2];
    int b = blockIdx.x, c = threadIdx.x; // blockDim 192
    ps[c] = pooled[b * CCH + c] * (1.0f / 16384.0f);
    __syncthreads();
    if (c < 24) {
        float t = 0.f;
        for (int k = 0; k < 192; ++k) t += ps[k] * ldin(w1, c * 192 + k, f1);
        g[c] = gelu_f(t);
    }
    __syncthreads();
    float s = 0.f;
#pragma unroll
    for (int r = 0; r < 24; ++r) s += g[r] * ldin(w2, c * 24 + r, f2);
    cm[b * CCH + c] = 1.0f / (1.0f + expf(-s));
}

// ---------- x2 = x + attn*cm + conv; write x2 (f32, into d_out) and n2 = LN(x2) ----------
__global__ __launch_bounds__(256)
void x2ln2_k(const void* __restrict__ x, const bf16* __restrict__ attnf,
             const bf16* __restrict__ conv, const float* __restrict__ cm,
             const void* __restrict__ w, const void* __restrict__ bb,
             float* __restrict__ x2, bf16* __restrict__ n2, const int* flags) {
    int fx = flags[FX], fw = flags[FN2W], fb = flags[FN2B];
    int wv = threadIdx.x >> 6, lane = threadIdx.x & 63;
    long long t = (long long)blockIdx.x * 4 + wv;
    int b = (int)(t >> 14);
    int l = (int)(t & 16383);
    int y = l >> 7, xx = l & 127;
    long long wrow = ((long long)b * 256 + (y >> 3) * 16 + (xx >> 3)) * 64 + (y & 7) * 8 + (xx & 7);

    float v[3];
#pragma unroll
    for (int k = 0; k < 3; ++k) {
        int c = lane + 64 * k;
        float val = ldin(x, t * CCH + c, fx)
                  + __bfloat162float(attnf[wrow * CCH + c]) * cm[b * CCH + c]
                  + __bfloat162float(conv[t * CCH + c]);
        v[k] = val;
        x2[t * CCH + c] = val;
    }
    float s = v[0] + v[1] + v[2];
    for (int o = 32; o; o >>= 1) s += __shfl_xor(s, o);
    float mean = s * (1.0f / 192.0f);
    float d[3] = {v[0] - mean, v[1] - mean, v[2] - mean};
    float vs = d[0] * d[0] + d[1] * d[1] + d[2] * d[2];
    for (int o = 32; o; o >>= 1) vs += __shfl_xor(vs, o);
    float rstd = rsqrtf(vs * (1.0f / 192.0f) + 1e-5f);
#pragma unroll
    for (int k = 0; k < 3; ++k) {
        int c = lane + 64 * k;
        n2[t * CCH + c] = __float2bfloat16(d[k] * rstd * ldin(w, c, fw) + ldin(bb, c, fb));
    }
}

// ---------- launch ----------
extern "C" void kernel_launch(void* const* d_in, const int* in_sizes, int n_in,
                              void* d_out, int out_size, void* d_ws, size_t ws_size,
                              hipStream_t stream) {
    (void)n_in; (void)out_size; (void)ws_size;
    float* out = (float*)d_out;

    char* wsp = (char*)d_ws;
    size_t off = 0;
    auto alloc = [&](size_t bytes) -> char* {
        char* p = wsp + off;
        off += (bytes + 255) & ~(size_t)255;
        return p;
    };
    int*  flags   = (int*)alloc(15 * 4);
    bf16* qkv_wT  = (bf16*)alloc(576 * 192 * 2);
    bf16* proj_wT = (bf16*)alloc(192 * 192 * 2);
    bf16* fc1_wT  = (bf16*)alloc(384 * 192 * 2);
    bf16* fc2_wT  = (bf16*)alloc(192 * 384 * 2);
    float* pooled = (float*)alloc(BATCH * CCH * 4);
    float* cm     = (float*)alloc(BATCH * CCH * 4);
    char* Rbig    = alloc(BL * 576 * 2);          // 150,994,944 B
    char* Rpair   = alloc(BL * 384 * 2);          // 100,663,296 B

    bf16* qkvb  = (bf16*)Rbig;                               // [BL,576]
    bf16* hbuf  = (bf16*)Rbig;                               // [BL,384] (after attn)
    bf16* attnf = (bf16*)(Rbig + (size_t)BL * 384 * 2);      // [BL,192] (tail of Rbig)
    bf16* n1    = (bf16*)Rpair;                              // [BL,192] -> n2
    bf16* cat   = (bf16*)(Rpair + (size_t)BL * 192 * 2);     // [BL,192] -> convf
    bf16* n2    = n1;
    bf16* convf = cat;
    bf16* h2    = (bf16*)Rpair;                              // [BL,384] (after fc1)
    float* x2   = out;                                       // x2 lives in d_out (f32)

    const int imap[15] = {0, 3, 4, 5, 6, 7, 8, 9, 10, 11, 12, 13, 14, 15, 16};
    InPtrs ip;
    for (int i = 0; i < 15; ++i) { ip.p[i] = d_in[imap[i]]; ip.n[i] = in_sizes[imap[i]]; }
    const void* x        = d_in[0];
    const void* qkv_w    = d_in[5];
    const void* proj_w   = d_in[6];
    const void* proj_b   = d_in[7];
    const void* attnbias = d_in[8];
    const void* conv_w   = d_in[9];
    const void* cg_w1    = d_in[10];
    const void* cg_w2    = d_in[11];
    const void* fc1_w    = d_in[14];
    const void* smix_w   = d_in[15];
    const void* fc2_w    = d_in[16];

    probe_k<<<15, 256, 0, stream>>>(ip, flags);

    transpose_k<<<(192 * 576 + 255) / 256, 256, 0, stream>>>(qkv_w, qkv_wT, 192, 576, flags + FQKVW);
    transpose_k<<<(192 * 192 + 255) / 256, 256, 0, stream>>>(proj_w, proj_wT, 192, 192, flags + FPROJW);
    transpose_k<<<(192 * 384 + 255) / 256, 256, 0, stream>>>(fc1_w, fc1_wT, 192, 384, flags + FFC1);
    transpose_k<<<(384 * 192 + 255) / 256, 256, 0, stream>>>(fc2_w, fc2_wT, 384, 192, flags + FFC2);
    hipMemsetAsync(pooled, 0, BATCH * CCH * 4, stream);

    // LN1
    ln_kernel<<<BL / 4, 256, 0, stream>>>(x, d_in[3], d_in[4], n1, flags);
    // qkv = n1 @ qkv_w  [BL,576]
    gemm_bt<0, 192, bf16><<<dim3(BL / 64, 576 / 64), 256, 0, stream>>>(n1, qkv_wT, qkvb, 576, nullptr, nullptr, flags);
    // MFMA window attention -> cat (window-ordered); 12288 (w,h) pairs, 4/block
    attn_mfma_k<<<NWIN * NHEADS / 4, 256, 0, stream>>>(qkvb, attnbias, cat, flags);
    // proj: attnf = cat @ proj_w + proj_b (window-ordered); qkv region now dead
    gemm_bt<1, 192, bf16><<<dim3(BL / 64, 192 / 64), 256, 0, stream>>>(cat, proj_wT, attnf, 192, proj_b, nullptr, flags);
    // conv branch: conv_feat = gelu(dwconv(n1)); overwrites cat (dead after proj)
    dwconv_k<true, 192><<<(BL * 192 + 255) / 256, 256, 0, stream>>>(n1, conv_w, convf, flags + FCONVW);
    // AIM gate
    pool_k<<<dim3(BATCH, 64), 192, 0, stream>>>(convf, pooled);
    cm_k<<<BATCH, 192, 0, stream>>>(pooled, cg_w1, cg_w2, cm, flags);
    // x2 (f32 -> d_out) + LN2 (n2 overwrites n1)
    x2ln2_k<<<BL / 4, 256, 0, stream>>>(x, attnf, convf, cm, d_in[12], d_in[13], x2, n2, flags);
    // FFN: h = gelu(n2 @ fc1_w) into front of Rbig (qkv+attnf dead)
    gemm_bt<2, 192, bf16><<<dim3(BL / 64, 384 / 64), 256, 0, stream>>>(n2, fc1_wT, hbuf, 384, nullptr, nullptr, flags);
    // spatial mix dwconv -> h2 (overwrites n2+convf, both dead)
    dwconv_k<false, 384><<<(BL * 384 + 255) / 256, 256, 0, stream>>>(hbuf, smix_w, h2, flags + FSMIX);
    // out = x2 + h2 @ fc2_w   (in-place f32 RMW on d_out)
    gemm_bt<3, 384, float><<<dim3(BL / 64, 192 / 64), 256, 0, stream>>>(h2, fc2_wT, out, 192, nullptr, x2, flags);
}